// Round 12
// baseline (289.219 us; speedup 1.0000x reference)
//
#include <hip/hip_runtime.h>
#include <hip/hip_bf16.h>
#include <hip/hip_fp16.h>
#include <math.h>

#define N_NODES 50000
#define N_HYPER 20000
#define N_EDGES_C 1000000
#define N_REL 256
#define DIM 128
#define SEM_DIM 64
#define CAP 128   // max edges per bucket; mean=50, sigma~7 -> ~11 sigma headroom

typedef unsigned int uint;
typedef unsigned short ushort;
typedef _Float16 v2h __attribute__((ext_vector_type(2)));
typedef _Float16 f16x8 __attribute__((ext_vector_type(8)));
typedef float f32x4 __attribute__((ext_vector_type(4)));

#define SC_2L2E 2.8853900817779268f   // 2*log2(e)
#define SC_L2E  1.4426950408889634f   // log2(e)

__device__ inline ushort f16rn(float f) { return __half_as_ushort(__float2half_rn(f)); }
__device__ inline __half2 u2h2(uint u) { return __builtin_bit_cast(__half2, u); }
__device__ inline uint pkh2(float a, float b) {
  return (uint)f16rn(a) | ((uint)f16rn(b) << 16);
}

__device__ inline float fdot2(__half2 a, __half2 b, float c) {
#if __has_builtin(__builtin_amdgcn_fdot2)
  return __builtin_amdgcn_fdot2(__builtin_bit_cast(v2h, a),
                                __builtin_bit_cast(v2h, b), c, false);
#else
  float2 fa = __half22float2(a), fb = __half22float2(b);
  return fmaf(fa.x, fb.x, fmaf(fa.y, fb.y, c));
#endif
}

__device__ inline uint getq(uint qv0, uint qv1, int src) {
  uint a = __shfl(qv0, src & 63, 64);
  uint b = __shfl(qv1, src & 63, 64);
  return (src < 64) ? a : b;
}

// blocks [0,256): sem_t; [256,512): weight transposes; [512,672): zero cnt
__global__ __launch_bounds__(128) void k_pre(
    const float* __restrict__ emb, const float* __restrict__ sem_w,
    const float* __restrict__ sem_b, ushort* __restrict__ sem_t_h,
    const float* __restrict__ Wr, const float* __restrict__ linw,
    ushort* __restrict__ WT_h, ushort* __restrict__ LW_h,
    int* __restrict__ cnt) {
  int b = blockIdx.x;
  int t = threadIdx.x;
  if (b < N_REL) {
    __shared__ float sW[DIM][SEM_DIM + 1];
    __shared__ float sE[SEM_DIM];
    for (int i = t; i < DIM * SEM_DIM; i += 128) sW[i / SEM_DIM][i % SEM_DIM] = sem_w[i];
    if (t < SEM_DIM) sE[t] = emb[b * SEM_DIM + t];
    __syncthreads();
    float acc = sem_b[t];
#pragma unroll 8
    for (int k = 0; k < SEM_DIM; ++k) acc = fmaf(sE[k], sW[t][k], acc);
    sem_t_h[b * DIM + t] = f16rn(acc * SC_2L2E);
  } else if (b < 512) {
    int i = (b - N_REL) * 128 + t;
    if (i < DIM * DIM) {
      int k = i >> 7, c = i & 127;
      WT_h[c * DIM + k] = f16rn(Wr[i]);
    } else {
      int j = i - DIM * DIM;
      LW_h[j] = f16rn(linw[j]);
    }
  } else {
    cnt[(b - 512) * 128 + t] = 0;
  }
}

// fused independent phases: blocks [0,SB) = edge scatter; [SB, SB+HB+NB) =
// MFMA producer GEMMs (rt from hyper, rh+ne from node).
#define SB 977
__global__ __launch_bounds__(256) void k_work(
    const int* __restrict__ sl, int* __restrict__ cnt, uint* __restrict__ ed,
    const float* __restrict__ hyper_emb, const float* __restrict__ node_emb,
    const ushort* __restrict__ WT_h, ushort* __restrict__ rt_h,
    ushort* __restrict__ rh_h, ushort* __restrict__ ne_h) {
  const int HB = (N_HYPER + 63) / 64;
  __shared__ uint smem[12288];   // 48 KB: sA 4096 uints + sB 8192 uints
  int b = blockIdx.x;
  int t = threadIdx.x;
  if (b < SB) {
    int e0 = (b * 256 + t) * 4;
    if (e0 >= N_EDGES_C) return;
    const int4* p = (const int4*)(sl + 3 * e0);
    int4 a = p[0], bb = p[1], c = p[2];
    int nd[4] = {a.x, a.w, bb.z, c.y};
    int hh[4] = {a.y, bb.x, bb.w, c.z};
    int rl[4] = {a.z, bb.y, c.x, c.w};
#pragma unroll
    for (int j = 0; j < 4; ++j) {
      int pos = atomicAdd(&cnt[hh[j]], 1);
      if (pos < CAP) ed[(size_t)hh[j] * CAP + pos] = (uint)nd[j] | ((uint)rl[j] << 16);
    }
    return;
  }
  uint* sA = smem;          // 64 rows x 128 halfs
  uint* sB0 = smem + 4096;  // 128 cols x 128 halfs
  int b2 = b - SB;
  bool isH = b2 < HB;
  const float* X = isH ? hyper_emb : node_emb;
  int bm = (isH ? b2 : b2 - HB) * 64;
  int M = isH ? N_HYPER : N_NODES;
  ushort* C0 = isH ? rt_h : rh_h;
  float scale0 = isH ? SC_2L2E : SC_L2E;
  int rows = min(64, M - bm);
  for (int ch = t; ch < 64 * 16; ch += 256) {
    int r = ch >> 4, c0 = ch & 15;
    uint4 v = {0u, 0u, 0u, 0u};
    if (r < rows) {
      const float4* gp = (const float4*)(X + (size_t)(bm + r) * DIM + c0 * 8);
      float4 x0 = gp[0], x1 = gp[1];
      v.x = pkh2(x0.x, x0.y); v.y = pkh2(x0.z, x0.w);
      v.z = pkh2(x1.x, x1.y); v.w = pkh2(x1.z, x1.w);
    }
    *(uint4*)&sA[r * 64 + ((c0 ^ (r & 15)) << 2)] = v;
  }
  for (int ch = t; ch < 128 * 16; ch += 256) {
    int c = ch >> 4, c0 = ch & 15;
    uint4 v = *(const uint4*)(WT_h + c * DIM + c0 * 8);
    *(uint4*)&sB0[c * 64 + ((c0 ^ (c & 15)) << 2)] = v;
  }
  __syncthreads();
  int wid = t >> 6, lane = t & 63;
  int arow = (wid << 4) + (lane & 15);
  int kg = lane >> 4;
  int cl = lane & 15;
  f32x4 acc0[8];
#pragma unroll
  for (int nt = 0; nt < 8; ++nt) acc0[nt] = (f32x4){0.f, 0.f, 0.f, 0.f};
#pragma unroll
  for (int ks = 0; ks < 4; ++ks) {
    int chA = (ks << 2) + kg;
    f16x8 afrag = *(const f16x8*)&sA[arow * 64 + ((chA ^ (arow & 15)) << 2)];
#pragma unroll
    for (int nt = 0; nt < 8; ++nt) {
      int col = (nt << 4) + cl;
      f16x8 b0 = *(const f16x8*)&sB0[col * 64 + ((chA ^ (col & 15)) << 2)];
      acc0[nt] = __builtin_amdgcn_mfma_f32_16x16x32_f16(afrag, b0, acc0[nt], 0, 0, 0);
    }
  }
  int rbase = (wid << 4) + (kg << 2);
#pragma unroll
  for (int nt = 0; nt < 8; ++nt) {
#pragma unroll
    for (int r = 0; r < 4; ++r) {
      int row = rbase + r;
      if (row < rows)
        C0[(size_t)(bm + row) * DIM + (nt << 4) + cl] = f16rn(acc0[nt][r] * scale0);
    }
  }
  if (!isH) {
    for (int ch = t; ch < 64 * 16; ch += 256) {
      int r = ch >> 4, c0 = ch & 15;
      if (r < rows) {
        uint4 v = *(uint4*)&sA[r * 64 + ((c0 ^ (r & 15)) << 2)];
        *(uint4*)(ne_h + (size_t)(bm + r) * DIM + c0 * 8) = v;
      }
    }
  }
}

// one wave per hyperedge (2/block); 8 groups x 8 lanes; bulk-q preload,
// uniform rounds; fp16 gathers, f32 accum, no softmax-max. Fused epilogue:
// row -> LDS (h2), per-lane 2-col matvec vs lin_w (fp16), wave LN, f32 out.
#define NG 8
#define BLK_H 2
__global__ __launch_bounds__(128) void k_agg(
    const ushort* __restrict__ rh_h, const ushort* __restrict__ rt_h,
    const ushort* __restrict__ semt_h, const ushort* __restrict__ ne_h,
    const uint* __restrict__ ed, const int* __restrict__ cnt,
    const ushort* __restrict__ LW_h, const float* __restrict__ bias,
    const float* __restrict__ gamma, const float* __restrict__ beta,
    float* __restrict__ out) {
  __shared__ uint rowbuf[BLK_H][64];   // agg row as 64 h2 words
  int wave = threadIdx.x >> 6;
  int lane = threadIdx.x & 63;
  int h = blockIdx.x * BLK_H + wave;
  int g = lane >> 3;
  int pos = lane & 7;
  int d0 = pos * 16;
  const uint4* tp = (const uint4*)(rt_h + ((size_t)h << 7) + d0);
  uint4 tba = tp[0], tbb = tp[1];
  __half2 tb0 = u2h2(tba.x), tb1 = u2h2(tba.y), tb2 = u2h2(tba.z), tb3 = u2h2(tba.w);
  __half2 tb4 = u2h2(tbb.x), tb5 = u2h2(tbb.y), tb6 = u2h2(tbb.z), tb7 = u2h2(tbb.w);
  const __half2 one2 = __floats2half2_rn(1.0f, 1.0f);
  const __half2 m2 = __floats2half2_rn(-2.0f, -2.0f);
  size_t base = (size_t)h * CAP;
  int n = min(cnt[h], CAP);
  uint qv0 = (lane < n) ? ed[base + lane] : 0u;
  uint qv1 = (64 + lane < n) ? ed[base + 64 + lane] : 0u;
  int rounds = (n + NG - 1) / NG;
  float l = 0.0f;
  float4 a0 = {0,0,0,0}, a1 = {0,0,0,0}, a2 = {0,0,0,0}, a3 = {0,0,0,0};

  for (int r = 0; r < rounds; ++r) {
    int e = r * NG + g;
    uint q = getq(qv0, qv1, e);
    int node = (int)(q & 0xffffu);
    int rel = (int)(q >> 16);
    const uint4* hp = (const uint4*)(rh_h + ((size_t)node << 7) + d0);
    const uint4* sp = (const uint4*)(semt_h + ((size_t)rel << 7) + d0);
    const uint4* np = (const uint4*)(ne_h + ((size_t)node << 7) + d0);
    uint4 ha = hp[0], hb = hp[1];
    uint4 sa = sp[0], sb = sp[1];
    uint4 na = np[0], nb = np[1];
    float da = 0.0f, db = 0.0f;
#define TP(US, UH, TB, ACC)                      \
    {                                            \
      __half2 arg = __hadd2(TB, u2h2(US));       \
      __half2 e2v = h2exp2(arg);                 \
      __half2 r2 = h2rcp(__hadd2(e2v, one2));    \
      __half2 t2 = __hfma2(m2, r2, one2);        \
      ACC = fdot2(u2h2(UH), t2, ACC);            \
    }
    TP(sa.x, ha.x, tb0, da) TP(sa.y, ha.y, tb1, db)
    TP(sa.z, ha.z, tb2, da) TP(sa.w, ha.w, tb3, db)
    TP(sb.x, hb.x, tb4, da) TP(sb.y, hb.y, tb5, db)
    TP(sb.z, hb.z, tb6, da) TP(sb.w, hb.w, tb7, db)
#undef TP
    float dot = da + db;   // = score * log2e (rh prescaled)
    dot += __shfl_xor(dot, 1, 64);
    dot += __shfl_xor(dot, 2, 64);
    dot += __shfl_xor(dot, 4, 64);
    float p = (e < n) ? exp2f(dot) : 0.0f;
    l += p;
    float2 n0 = __half22float2(u2h2(na.x));
    float2 n1 = __half22float2(u2h2(na.y));
    float2 n2 = __half22float2(u2h2(na.z));
    float2 n3 = __half22float2(u2h2(na.w));
    float2 n4 = __half22float2(u2h2(nb.x));
    float2 n5 = __half22float2(u2h2(nb.y));
    float2 n6 = __half22float2(u2h2(nb.z));
    float2 n7 = __half22float2(u2h2(nb.w));
    a0.x = fmaf(p, n0.x, a0.x); a0.y = fmaf(p, n0.y, a0.y);
    a0.z = fmaf(p, n1.x, a0.z); a0.w = fmaf(p, n1.y, a0.w);
    a1.x = fmaf(p, n2.x, a1.x); a1.y = fmaf(p, n2.y, a1.y);
    a1.z = fmaf(p, n3.x, a1.z); a1.w = fmaf(p, n3.y, a1.w);
    a2.x = fmaf(p, n4.x, a2.x); a2.y = fmaf(p, n4.y, a2.y);
    a2.z = fmaf(p, n5.x, a2.z); a2.w = fmaf(p, n5.y, a2.w);
    a3.x = fmaf(p, n6.x, a3.x); a3.y = fmaf(p, n6.y, a3.y);
    a3.z = fmaf(p, n7.x, a3.z); a3.w = fmaf(p, n7.y, a3.w);
  }
#pragma unroll
  for (int mo = 8; mo < 64; mo <<= 1) {
    l += __shfl_xor(l, mo, 64);
    a0.x += __shfl_xor(a0.x, mo, 64); a0.y += __shfl_xor(a0.y, mo, 64);
    a0.z += __shfl_xor(a0.z, mo, 64); a0.w += __shfl_xor(a0.w, mo, 64);
    a1.x += __shfl_xor(a1.x, mo, 64); a1.y += __shfl_xor(a1.y, mo, 64);
    a1.z += __shfl_xor(a1.z, mo, 64); a1.w += __shfl_xor(a1.w, mo, 64);
    a2.x += __shfl_xor(a2.x, mo, 64); a2.y += __shfl_xor(a2.y, mo, 64);
    a2.z += __shfl_xor(a2.z, mo, 64); a2.w += __shfl_xor(a2.w, mo, 64);
    a3.x += __shfl_xor(a3.x, mo, 64); a3.y += __shfl_xor(a3.y, mo, 64);
    a3.z += __shfl_xor(a3.z, mo, 64); a3.w += __shfl_xor(a3.w, mo, 64);
  }
  if (g == 0) {
    float inv = (l > 0.0f) ? __builtin_amdgcn_rcpf(l) : 0.0f;
    uint4 w0, w1;
    w0.x = pkh2(a0.x * inv, a0.y * inv); w0.y = pkh2(a0.z * inv, a0.w * inv);
    w0.z = pkh2(a1.x * inv, a1.y * inv); w0.w = pkh2(a1.z * inv, a1.w * inv);
    w1.x = pkh2(a2.x * inv, a2.y * inv); w1.y = pkh2(a2.z * inv, a2.w * inv);
    w1.z = pkh2(a3.x * inv, a3.y * inv); w1.w = pkh2(a3.z * inv, a3.w * inv);
    *(uint4*)&rowbuf[wave][pos * 8] = w0;
    *(uint4*)&rowbuf[wave][pos * 8 + 4] = w1;
  }
  __syncthreads();
  // matvec: this lane computes output cols (lane) and (lane+64)
  const uint4* rp = (const uint4*)rowbuf[wave];
  const uint4* lw0 = (const uint4*)(LW_h + lane * DIM);
  const uint4* lw1 = (const uint4*)(LW_h + (lane + 64) * DIM);
  float s0 = 0.0f, s1 = 0.0f;
#pragma unroll
  for (int kk = 0; kk < 16; ++kk) {
    uint4 rw = rp[kk];
    uint4 w0 = lw0[kk], w1 = lw1[kk];
    s0 = fdot2(u2h2(rw.x), u2h2(w0.x), s0);
    s0 = fdot2(u2h2(rw.y), u2h2(w0.y), s0);
    s0 = fdot2(u2h2(rw.z), u2h2(w0.z), s0);
    s0 = fdot2(u2h2(rw.w), u2h2(w0.w), s0);
    s1 = fdot2(u2h2(rw.x), u2h2(w1.x), s1);
    s1 = fdot2(u2h2(rw.y), u2h2(w1.y), s1);
    s1 = fdot2(u2h2(rw.z), u2h2(w1.z), s1);
    s1 = fdot2(u2h2(rw.w), u2h2(w1.w), s1);
  }
  float v0 = s0 + bias[lane];
  float v1 = s1 + bias[lane + 64];
  v0 = v0 >= 0.0f ? v0 : 0.01f * v0;
  v1 = v1 >= 0.0f ? v1 : 0.01f * v1;
  float sum = v0 + v1, sq = v0 * v0 + v1 * v1;
#pragma unroll
  for (int mo = 1; mo < 64; mo <<= 1) {
    sum += __shfl_xor(sum, mo, 64);
    sq += __shfl_xor(sq, mo, 64);
  }
  float mu = sum * (1.0f / 128.0f);
  float var = sq * (1.0f / 128.0f) - mu * mu;
  float inv2 = rsqrtf(var + 1e-5f);
  float* Or = out + ((size_t)h << 7);
  Or[lane] = (v0 - mu) * inv2 * gamma[lane] + beta[lane];
  Or[lane + 64] = (v1 - mu) * inv2 * gamma[lane + 64] + beta[lane + 64];
}

extern "C" void kernel_launch(void* const* d_in, const int* in_sizes, int n_in,
                              void* d_out, int out_size, void* d_ws, size_t ws_size,
                              hipStream_t stream) {
  const float* node_emb = (const float*)d_in[0];
  const float* sem_emb = (const float*)d_in[1];
  const float* hyper_emb = (const float*)d_in[2];
  const float* W_r = (const float*)d_in[3];
  const float* lin_w = (const float*)d_in[4];
  const float* lin_b = (const float*)d_in[5];
  const float* sem_w = (const float*)d_in[6];
  const float* sem_b = (const float*)d_in[7];
  const float* ln_g = (const float*)d_in[8];
  const float* ln_b = (const float*)d_in[9];
  const int* sl = (const int*)d_in[10];
  float* out = (float*)d_out;

  // all segments 256-byte aligned
  char* ws = (char*)d_ws;
  int* cnt = (int*)(ws + 5120000);                // 20,480 ints
  uint* ed = (uint*)(ws + 5201920);               // 2,560,000 u32
  ushort* rt_h = (ushort*)(ws + 15441920);        // 2,560,000 halfs
  ushort* rh_h = (ushort*)(ws + 20561920);        // 6,400,000 halfs
  ushort* ne_h = (ushort*)(ws + 33361920);        // 6,400,000 halfs
  ushort* semt_h = (ushort*)(ws + 46161920);      // 32,768 halfs
  ushort* WT_h = (ushort*)(ws + 46227456);        // 16,384 halfs
  ushort* LW_h = (ushort*)(ws + 46260224);        // 16,384 halfs

  const int HB = (N_HYPER + 63) / 64;
  const int NB = (N_NODES + 63) / 64;
  k_pre<<<672, 128, 0, stream>>>(sem_emb, sem_w, sem_b, semt_h,
                                 W_r, lin_w, WT_h, LW_h, cnt);
  k_work<<<SB + HB + NB, 256, 0, stream>>>(sl, cnt, ed, hyper_emb, node_emb,
                                           WT_h, rt_h, rh_h, ne_h);
  k_agg<<<N_HYPER / BLK_H, 128, 0, stream>>>(rh_h, rt_h, semt_h, ne_h, ed, cnt,
                                             LW_h, lin_b, ln_g, ln_b, out);
}

// Round 13
// 237.720 us; speedup vs baseline: 1.2166x; 1.2166x over previous
//
#include <hip/hip_runtime.h>
#include <hip/hip_bf16.h>
#include <hip/hip_fp16.h>
#include <math.h>

#define N_NODES 50000
#define N_HYPER 20000
#define N_EDGES_C 1000000
#define N_REL 256
#define DIM 128
#define SEM_DIM 64
#define CAP 128   // max edges per bucket; mean=50, sigma~7 -> ~11 sigma headroom

typedef unsigned int uint;
typedef unsigned short ushort;
typedef _Float16 v2h __attribute__((ext_vector_type(2)));
typedef _Float16 f16x8 __attribute__((ext_vector_type(8)));
typedef float f32x4 __attribute__((ext_vector_type(4)));

#define SC_2L2E 2.8853900817779268f   // 2*log2(e)
#define SC_L2E  1.4426950408889634f   // log2(e)

__device__ inline ushort f16rn(float f) { return __half_as_ushort(__float2half_rn(f)); }
__device__ inline __half2 u2h2(uint u) { return __builtin_bit_cast(__half2, u); }
__device__ inline uint pkh2(float a, float b) {
  return (uint)f16rn(a) | ((uint)f16rn(b) << 16);
}

__device__ inline float fdot2(__half2 a, __half2 b, float c) {
#if __has_builtin(__builtin_amdgcn_fdot2)
  return __builtin_amdgcn_fdot2(__builtin_bit_cast(v2h, a),
                                __builtin_bit_cast(v2h, b), c, false);
#else
  float2 fa = __half22float2(a), fb = __half22float2(b);
  return fmaf(fa.x, fb.x, fmaf(fa.y, fb.y, c));
#endif
}

// blocks [0,256): sem_t; [256,512): weight transposes; [512,672): zero cnt
__global__ __launch_bounds__(128) void k_pre(
    const float* __restrict__ emb, const float* __restrict__ sem_w,
    const float* __restrict__ sem_b, ushort* __restrict__ sem_t_h,
    const float* __restrict__ Wr, const float* __restrict__ linw,
    ushort* __restrict__ WT_h, ushort* __restrict__ LW_h,
    int* __restrict__ cnt) {
  int b = blockIdx.x;
  int t = threadIdx.x;
  if (b < N_REL) {
    __shared__ float sW[DIM][SEM_DIM + 1];
    __shared__ float sE[SEM_DIM];
    for (int i = t; i < DIM * SEM_DIM; i += 128) sW[i / SEM_DIM][i % SEM_DIM] = sem_w[i];
    if (t < SEM_DIM) sE[t] = emb[b * SEM_DIM + t];
    __syncthreads();
    float acc = sem_b[t];
#pragma unroll 8
    for (int k = 0; k < SEM_DIM; ++k) acc = fmaf(sE[k], sW[t][k], acc);
    sem_t_h[b * DIM + t] = f16rn(acc * SC_2L2E);
  } else if (b < 512) {
    int i = (b - N_REL) * 128 + t;
    if (i < DIM * DIM) {
      int k = i >> 7, c = i & 127;
      WT_h[c * DIM + k] = f16rn(Wr[i]);
    } else {
      int j = i - DIM * DIM;
      LW_h[j] = f16rn(linw[j]);
    }
  } else {
    cnt[(b - 512) * 128 + t] = 0;
  }
}

// fused independent phases: blocks [0,SB) = edge scatter; [SB, SB+HB+NB) =
// MFMA producer GEMMs (rt from hyper, rh+ne from node).
#define SB 977
__global__ __launch_bounds__(256) void k_work(
    const int* __restrict__ sl, int* __restrict__ cnt, uint* __restrict__ ed,
    const float* __restrict__ hyper_emb, const float* __restrict__ node_emb,
    const ushort* __restrict__ WT_h, ushort* __restrict__ rt_h,
    ushort* __restrict__ rh_h, ushort* __restrict__ ne_h) {
  const int HB = (N_HYPER + 63) / 64;
  __shared__ uint smem[12288];   // 48 KB: sA 4096 uints + sB 8192 uints
  int b = blockIdx.x;
  int t = threadIdx.x;
  if (b < SB) {
    int e0 = (b * 256 + t) * 4;
    if (e0 >= N_EDGES_C) return;
    const int4* p = (const int4*)(sl + 3 * e0);
    int4 a = p[0], bb = p[1], c = p[2];
    int nd[4] = {a.x, a.w, bb.z, c.y};
    int hh[4] = {a.y, bb.x, bb.w, c.z};
    int rl[4] = {a.z, bb.y, c.x, c.w};
#pragma unroll
    for (int j = 0; j < 4; ++j) {
      int pos = atomicAdd(&cnt[hh[j]], 1);
      if (pos < CAP) ed[(size_t)hh[j] * CAP + pos] = (uint)nd[j] | ((uint)rl[j] << 16);
    }
    return;
  }
  uint* sA = smem;          // 64 rows x 128 halfs
  uint* sB0 = smem + 4096;  // 128 cols x 128 halfs
  int b2 = b - SB;
  bool isH = b2 < HB;
  const float* X = isH ? hyper_emb : node_emb;
  int bm = (isH ? b2 : b2 - HB) * 64;
  int M = isH ? N_HYPER : N_NODES;
  ushort* C0 = isH ? rt_h : rh_h;
  float scale0 = isH ? SC_2L2E : SC_L2E;
  int rows = min(64, M - bm);
  for (int ch = t; ch < 64 * 16; ch += 256) {
    int r = ch >> 4, c0 = ch & 15;
    uint4 v = {0u, 0u, 0u, 0u};
    if (r < rows) {
      const float4* gp = (const float4*)(X + (size_t)(bm + r) * DIM + c0 * 8);
      float4 x0 = gp[0], x1 = gp[1];
      v.x = pkh2(x0.x, x0.y); v.y = pkh2(x0.z, x0.w);
      v.z = pkh2(x1.x, x1.y); v.w = pkh2(x1.z, x1.w);
    }
    *(uint4*)&sA[r * 64 + ((c0 ^ (r & 15)) << 2)] = v;
  }
  for (int ch = t; ch < 128 * 16; ch += 256) {
    int c = ch >> 4, c0 = ch & 15;
    uint4 v = *(const uint4*)(WT_h + c * DIM + c0 * 8);
    *(uint4*)&sB0[c * 64 + ((c0 ^ (c & 15)) << 2)] = v;
  }
  __syncthreads();
  int wid = t >> 6, lane = t & 63;
  int arow = (wid << 4) + (lane & 15);
  int kg = lane >> 4;
  int cl = lane & 15;
  f32x4 acc0[8];
#pragma unroll
  for (int nt = 0; nt < 8; ++nt) acc0[nt] = (f32x4){0.f, 0.f, 0.f, 0.f};
#pragma unroll
  for (int ks = 0; ks < 4; ++ks) {
    int chA = (ks << 2) + kg;
    f16x8 afrag = *(const f16x8*)&sA[arow * 64 + ((chA ^ (arow & 15)) << 2)];
#pragma unroll
    for (int nt = 0; nt < 8; ++nt) {
      int col = (nt << 4) + cl;
      f16x8 b0 = *(const f16x8*)&sB0[col * 64 + ((chA ^ (col & 15)) << 2)];
      acc0[nt] = __builtin_amdgcn_mfma_f32_16x16x32_f16(afrag, b0, acc0[nt], 0, 0, 0);
    }
  }
  int rbase = (wid << 4) + (kg << 2);
#pragma unroll
  for (int nt = 0; nt < 8; ++nt) {
#pragma unroll
    for (int r = 0; r < 4; ++r) {
      int row = rbase + r;
      if (row < rows)
        C0[(size_t)(bm + row) * DIM + (nt << 4) + cl] = f16rn(acc0[nt][r] * scale0);
    }
  }
  if (!isH) {
    for (int ch = t; ch < 64 * 16; ch += 256) {
      int r = ch >> 4, c0 = ch & 15;
      if (r < rows) {
        uint4 v = *(uint4*)&sA[r * 64 + ((c0 ^ (r & 15)) << 2)];
        *(uint4*)(ne_h + (size_t)(bm + r) * DIM + c0 * 8) = v;
      }
    }
  }
}

// one wave per hyperedge (2/block); 8 groups x 8 lanes; group owns one edge
// per round, lane owns 16 dims. fp16 gathers, f32 accum, no softmax-max.
// (r10-proven loop: direct ed reads, no prefetch, no barrier.) fp16 output.
#define NG 8
#define BLK_H 2
__global__ __launch_bounds__(128) void k_agg(
    const ushort* __restrict__ rh_h, const ushort* __restrict__ rt_h,
    const ushort* __restrict__ semt_h, const ushort* __restrict__ ne_h,
    const uint* __restrict__ ed, const int* __restrict__ cnt,
    ushort* __restrict__ agg_h) {
  int wave = threadIdx.x >> 6;
  int lane = threadIdx.x & 63;
  int h = blockIdx.x * BLK_H + wave;
  int g = lane >> 3;
  int pos = lane & 7;
  int d0 = pos * 16;
  const uint4* tp = (const uint4*)(rt_h + ((size_t)h << 7) + d0);
  uint4 tba = tp[0], tbb = tp[1];
  __half2 tb0 = u2h2(tba.x), tb1 = u2h2(tba.y), tb2 = u2h2(tba.z), tb3 = u2h2(tba.w);
  __half2 tb4 = u2h2(tbb.x), tb5 = u2h2(tbb.y), tb6 = u2h2(tbb.z), tb7 = u2h2(tbb.w);
  const __half2 one2 = __floats2half2_rn(1.0f, 1.0f);
  const __half2 m2 = __floats2half2_rn(-2.0f, -2.0f);
  size_t base = (size_t)h * CAP;
  int n = min(cnt[h], CAP);
  float l = 0.0f;
  float4 a0 = {0,0,0,0}, a1 = {0,0,0,0}, a2 = {0,0,0,0}, a3 = {0,0,0,0};

  for (int e = g; e < n; e += NG) {
    uint q = ed[base + e];
    int node = (int)(q & 0xffffu);
    int rel = (int)(q >> 16);
    const uint4* hp = (const uint4*)(rh_h + ((size_t)node << 7) + d0);
    const uint4* sp = (const uint4*)(semt_h + ((size_t)rel << 7) + d0);
    const uint4* np = (const uint4*)(ne_h + ((size_t)node << 7) + d0);
    uint4 ha = hp[0], hb = hp[1];
    uint4 sa = sp[0], sb = sp[1];
    uint4 na = np[0], nb = np[1];
    float da = 0.0f, db = 0.0f;
#define TP(US, UH, TB, ACC)                      \
    {                                            \
      __half2 arg = __hadd2(TB, u2h2(US));       \
      __half2 e2v = h2exp2(arg);                 \
      __half2 r2 = h2rcp(__hadd2(e2v, one2));    \
      __half2 t2 = __hfma2(m2, r2, one2);        \
      ACC = fdot2(u2h2(UH), t2, ACC);            \
    }
    TP(sa.x, ha.x, tb0, da) TP(sa.y, ha.y, tb1, db)
    TP(sa.z, ha.z, tb2, da) TP(sa.w, ha.w, tb3, db)
    TP(sb.x, hb.x, tb4, da) TP(sb.y, hb.y, tb5, db)
    TP(sb.z, hb.z, tb6, da) TP(sb.w, hb.w, tb7, db)
#undef TP
    float dot = da + db;   // = score * log2e (rh prescaled)
    dot += __shfl_xor(dot, 1, 64);
    dot += __shfl_xor(dot, 2, 64);
    dot += __shfl_xor(dot, 4, 64);
    float p = exp2f(dot);
    l += p;
    float2 n0 = __half22float2(u2h2(na.x));
    float2 n1 = __half22float2(u2h2(na.y));
    float2 n2 = __half22float2(u2h2(na.z));
    float2 n3 = __half22float2(u2h2(na.w));
    float2 n4 = __half22float2(u2h2(nb.x));
    float2 n5 = __half22float2(u2h2(nb.y));
    float2 n6 = __half22float2(u2h2(nb.z));
    float2 n7 = __half22float2(u2h2(nb.w));
    a0.x = fmaf(p, n0.x, a0.x); a0.y = fmaf(p, n0.y, a0.y);
    a0.z = fmaf(p, n1.x, a0.z); a0.w = fmaf(p, n1.y, a0.w);
    a1.x = fmaf(p, n2.x, a1.x); a1.y = fmaf(p, n2.y, a1.y);
    a1.z = fmaf(p, n3.x, a1.z); a1.w = fmaf(p, n3.y, a1.w);
    a2.x = fmaf(p, n4.x, a2.x); a2.y = fmaf(p, n4.y, a2.y);
    a2.z = fmaf(p, n5.x, a2.z); a2.w = fmaf(p, n5.y, a2.w);
    a3.x = fmaf(p, n6.x, a3.x); a3.y = fmaf(p, n6.y, a3.y);
    a3.z = fmaf(p, n7.x, a3.z); a3.w = fmaf(p, n7.y, a3.w);
  }
#pragma unroll
  for (int mo = 8; mo < 64; mo <<= 1) {
    l += __shfl_xor(l, mo, 64);
    a0.x += __shfl_xor(a0.x, mo, 64); a0.y += __shfl_xor(a0.y, mo, 64);
    a0.z += __shfl_xor(a0.z, mo, 64); a0.w += __shfl_xor(a0.w, mo, 64);
    a1.x += __shfl_xor(a1.x, mo, 64); a1.y += __shfl_xor(a1.y, mo, 64);
    a1.z += __shfl_xor(a1.z, mo, 64); a1.w += __shfl_xor(a1.w, mo, 64);
    a2.x += __shfl_xor(a2.x, mo, 64); a2.y += __shfl_xor(a2.y, mo, 64);
    a2.z += __shfl_xor(a2.z, mo, 64); a2.w += __shfl_xor(a2.w, mo, 64);
    a3.x += __shfl_xor(a3.x, mo, 64); a3.y += __shfl_xor(a3.y, mo, 64);
    a3.z += __shfl_xor(a3.z, mo, 64); a3.w += __shfl_xor(a3.w, mo, 64);
  }
  if (g == 0) {
    float inv = (l > 0.0f) ? __builtin_amdgcn_rcpf(l) : 0.0f;
    uint4 w0, w1;
    w0.x = pkh2(a0.x * inv, a0.y * inv); w0.y = pkh2(a0.z * inv, a0.w * inv);
    w0.z = pkh2(a1.x * inv, a1.y * inv); w0.w = pkh2(a1.z * inv, a1.w * inv);
    w1.x = pkh2(a2.x * inv, a2.y * inv); w1.y = pkh2(a2.z * inv, a2.w * inv);
    w1.z = pkh2(a3.x * inv, a3.y * inv); w1.w = pkh2(a3.z * inv, a3.w * inv);
    *(uint4*)(agg_h + ((size_t)h << 7) + d0) = w0;
    *(uint4*)(agg_h + ((size_t)h << 7) + d0 + 8) = w1;
  }
}

// final: C = agg @ lin_w.T (MFMA fp16), fused bias+LeakyReLU+LayerNorm epilogue
__global__ __launch_bounds__(256) void k_mfma_ln(
    const ushort* __restrict__ Ah, const ushort* __restrict__ LWh,
    const float* __restrict__ bias, const float* __restrict__ gamma,
    const float* __restrict__ beta, float* __restrict__ out, int M) {
  __shared__ uint sA[64 * 64];
  __shared__ uint sB0[128 * 64];
  int t = threadIdx.x;
  int bm = blockIdx.x * 64;
  int rows = min(64, M - bm);
  for (int ch = t; ch < 64 * 16; ch += 256) {
    int r = ch >> 4, c0 = ch & 15;
    uint4 v = {0u, 0u, 0u, 0u};
    if (r < rows) v = *(const uint4*)(Ah + (size_t)(bm + r) * DIM + c0 * 8);
    *(uint4*)&sA[r * 64 + ((c0 ^ (r & 15)) << 2)] = v;
  }
  for (int ch = t; ch < 128 * 16; ch += 256) {
    int c = ch >> 4, c0 = ch & 15;
    uint4 v = *(const uint4*)(LWh + c * DIM + c0 * 8);
    *(uint4*)&sB0[c * 64 + ((c0 ^ (c & 15)) << 2)] = v;
  }
  __syncthreads();
  int wid = t >> 6, lane = t & 63;
  int arow = (wid << 4) + (lane & 15);
  int kg = lane >> 4;
  int cl = lane & 15;
  f32x4 acc0[8];
#pragma unroll
  for (int nt = 0; nt < 8; ++nt) acc0[nt] = (f32x4){0.f, 0.f, 0.f, 0.f};
#pragma unroll
  for (int ks = 0; ks < 4; ++ks) {
    int chA = (ks << 2) + kg;
    f16x8 afrag = *(const f16x8*)&sA[arow * 64 + ((chA ^ (arow & 15)) << 2)];
#pragma unroll
    for (int nt = 0; nt < 8; ++nt) {
      int col = (nt << 4) + cl;
      f16x8 b0 = *(const f16x8*)&sB0[col * 64 + ((chA ^ (col & 15)) << 2)];
      acc0[nt] = __builtin_amdgcn_mfma_f32_16x16x32_f16(afrag, b0, acc0[nt], 0, 0, 0);
    }
  }
  float bv[8], gv[8], ev[8];
#pragma unroll
  for (int nt = 0; nt < 8; ++nt) {
    int col = (nt << 4) + cl;
    bv[nt] = bias[col]; gv[nt] = gamma[col]; ev[nt] = beta[col];
  }
  int rbase = (wid << 4) + (kg << 2);
#pragma unroll
  for (int r = 0; r < 4; ++r) {
    float s = 0.f, q = 0.f;
#pragma unroll
    for (int nt = 0; nt < 8; ++nt) {
      float x = acc0[nt][r] + bv[nt];
      x = x >= 0.0f ? x : 0.01f * x;
      acc0[nt][r] = x;
      s += x; q += x * x;
    }
#pragma unroll
    for (int mo = 1; mo < 16; mo <<= 1) {
      s += __shfl_xor(s, mo, 64);
      q += __shfl_xor(q, mo, 64);
    }
    float mu = s * (1.0f / 128.0f);
    float var = q * (1.0f / 128.0f) - mu * mu;
    float inv = rsqrtf(var + 1e-5f);
    int row = rbase + r;
    if (row < rows) {
      float* Or = out + (size_t)(bm + row) * DIM;
#pragma unroll
      for (int nt = 0; nt < 8; ++nt)
        Or[(nt << 4) + cl] = (acc0[nt][r] - mu) * inv * gv[nt] + ev[nt];
    }
  }
}

extern "C" void kernel_launch(void* const* d_in, const int* in_sizes, int n_in,
                              void* d_out, int out_size, void* d_ws, size_t ws_size,
                              hipStream_t stream) {
  const float* node_emb = (const float*)d_in[0];
  const float* sem_emb = (const float*)d_in[1];
  const float* hyper_emb = (const float*)d_in[2];
  const float* W_r = (const float*)d_in[3];
  const float* lin_w = (const float*)d_in[4];
  const float* lin_b = (const float*)d_in[5];
  const float* sem_w = (const float*)d_in[6];
  const float* sem_b = (const float*)d_in[7];
  const float* ln_g = (const float*)d_in[8];
  const float* ln_b = (const float*)d_in[9];
  const int* sl = (const int*)d_in[10];
  float* out = (float*)d_out;

  // all segments 256-byte aligned
  char* ws = (char*)d_ws;
  ushort* agg_h = (ushort*)ws;                    // 2,560,000 halfs
  int* cnt = (int*)(ws + 5120000);                // 20,480 ints
  uint* ed = (uint*)(ws + 5201920);               // 2,560,000 u32
  ushort* rt_h = (ushort*)(ws + 15441920);        // 2,560,000 halfs
  ushort* rh_h = (ushort*)(ws + 20561920);        // 6,400,000 halfs
  ushort* ne_h = (ushort*)(ws + 33361920);        // 6,400,000 halfs
  ushort* semt_h = (ushort*)(ws + 46161920);      // 32,768 halfs
  ushort* WT_h = (ushort*)(ws + 46227456);        // 16,384 halfs
  ushort* LW_h = (ushort*)(ws + 46260224);        // 16,384 halfs

  const int HB = (N_HYPER + 63) / 64;
  const int NB = (N_NODES + 63) / 64;
  k_pre<<<672, 128, 0, stream>>>(sem_emb, sem_w, sem_b, semt_h,
                                 W_r, lin_w, WT_h, LW_h, cnt);
  k_work<<<SB + HB + NB, 256, 0, stream>>>(sl, cnt, ed, hyper_emb, node_emb,
                                           WT_h, rt_h, rh_h, ne_h);
  k_agg<<<N_HYPER / BLK_H, 128, 0, stream>>>(rh_h, rt_h, semt_h, ne_h, ed, cnt, agg_h);
  k_mfma_ln<<<HB, 256, 0, stream>>>(agg_h, LW_h, lin_b, ln_g, ln_b, out, N_HYPER);
}